// Round 11
// baseline (54.875 us; speedup 1.0000x reference)
//
#include <hip/hip_runtime.h>
#include <math.h>

#define NN 129
#define INC 129
#define OUTC 64
#define NE 4096
#define NGRU 521        // GRU blocks; 521*16 waves*2 jobs = 16672 >= 16641
#define WCAP 32         // per-wave edge-list capacity (mean ~2, max ~10)

__device__ __forceinline__ float sigmf(float x) { return 1.0f / (1.0f + expf(-x)); }

// D1: blocks [0,NGRU): per-block redundant scores+rank, then GRU (2 jobs/wave);
//     blocks [NGRU,NGRU+129): per-target-node gather -> agg row (no global atomics)
__global__ __launch_bounds__(1024) void k_big(
    const float* __restrict__ x, const int* __restrict__ ei,
    const float* __restrict__ ew, const float* __restrict__ p,
    const float* __restrict__ W0, const float* __restrict__ w_ih,
    const float* __restrict__ w_hh, const float* __restrict__ b_ih,
    const float* __restrict__ b_hh, float* __restrict__ W,
    float* __restrict__ agg)
{
    int b = blockIdx.x, t = threadIdx.x;
    int wv = t >> 6, lane = t & 63;
    const int* row = ei;
    const int* col = ei + NE;

    if (b < NGRU) {
        __shared__ float s_sc[NN];
        __shared__ int   s_perm[NN];
        __shared__ float s_rinv;
        if (wv == 0) {
            float a = 0.f;
            for (int c = lane; c < INC; c += 64) { float pv = p[c]; a += pv * pv; }
            for (int o = 32; o; o >>= 1) a += __shfl_xor(a, o, 64);
            if (lane == 0) s_rinv = 1.0f / sqrtf(a);
        }
        // wave-parallel raw dots: wave wv -> nodes wv, wv+16, ...
        for (int n = wv; n < NN; n += 16) {
            const float* xr = x + (size_t)n * INC;
            float a = 0.f;
            for (int c = lane; c < INC; c += 64) a += xr[c] * p[c];
            for (int o = 32; o; o >>= 1) a += __shfl_xor(a, o, 64);
            if (lane == 0) s_sc[n] = a;
        }
        __syncthreads();
        if (t < NN) s_sc[t] = tanhf(s_sc[t] * s_rinv);
        __syncthreads();
        if (t < NN) {
            float my = s_sc[t];
            int rank = 0;
            #pragma unroll 16
            for (int j = 0; j < NN; ++j) {
                float o = s_sc[j];
                rank += (o > my || (o == my && j < t)) ? 1 : 0;   // stable descending
            }
            s_perm[rank] = t;
        }
        __syncthreads();

        int gw = b * 16 + wv;
        #pragma unroll
        for (int jj = 0; jj < 2; ++jj) {
            int wid = gw * 2 + jj;
            if (wid >= NN * INC) continue;
            int i = wid / INC;
            int j = wid - i * INC;
            int pi = s_perm[i];
            float sc = s_sc[pi];
            const float* xr = x  + (size_t)pi * INC;
            const float* h0 = W0 + (size_t)i * INC;
            const float* wr = w_ih + (size_t)j * INC;
            const float* wz = wr + (size_t)INC * INC;
            const float* wn = wz + (size_t)INC * INC;
            const float* vr = w_hh + (size_t)j * INC;
            const float* vz = vr + (size_t)INC * INC;
            const float* vn = vz + (size_t)INC * INC;

            float sr = 0.f, szv = 0.f, an = 0.f, hn = 0.f;
            for (int c = lane; c < INC; c += 64) {
                float xv = xr[c] * sc;
                float hv = h0[c];
                sr  += xv * wr[c] + hv * vr[c];
                szv += xv * wz[c] + hv * vz[c];
                an  += xv * wn[c];
                hn  += hv * vn[c];
            }
            for (int o = 32; o; o >>= 1) {
                sr  += __shfl_xor(sr,  o, 64);
                szv += __shfl_xor(szv, o, 64);
                an  += __shfl_xor(an,  o, 64);
                hn  += __shfl_xor(hn,  o, 64);
            }
            if (lane == 0) {
                float r    = sigmf(sr  + b_ih[j]           + b_hh[j]);
                float z    = sigmf(szv + b_ih[INC + j]     + b_hh[INC + j]);
                float cand = tanhf(an + b_ih[2 * INC + j] + r * (hn + b_hh[2 * INC + j]));
                W[(size_t)i * INC + j] = (1.0f - z) * cand + z * h0[j];
            }
        }
    } else {
        // gather block for target node c
        int c = b - NGRU;
        __shared__ float s_deg[NN];
        __shared__ float s_dis[NN];
        __shared__ int   s_r[16 * WCAP];
        __shared__ float s_w[16 * WCAP];
        __shared__ int   s_cnt[16];
        __shared__ int   s_off[17];
        __shared__ int   s_dr[16 * WCAP];
        __shared__ float s_nrm[16 * WCAP];

        if (t < NN) s_deg[t] = 0.f;
        __syncthreads();
        for (int e = t; e < NE; e += 1024) atomicAdd(&s_deg[col[e]], ew[e]);
        __syncthreads();
        if (t < NN) s_dis[t] = rsqrtf(fmaxf(s_deg[t] + 1.0f, 1e-12f));  // +1 self-loop
        __syncthreads();

        // syncless per-wave ballot edge-list: wave wv owns edges [wv*256, wv*256+256)
        int basee = wv * 256;
        int cnt = 0;
        #pragma unroll
        for (int it = 0; it < 4; ++it) {
            int e = basee + it * 64 + lane;
            int rr = row[e];
            float wval = ew[e];
            bool m = (col[e] == c);
            unsigned long long mask = __ballot(m);
            if (m) {
                int pos = cnt + __popcll(mask & ((1ull << lane) - 1));
                if (pos < WCAP) { s_r[wv * WCAP + pos] = rr; s_w[wv * WCAP + pos] = wval; }
            }
            cnt += __popcll(mask);
        }
        if (lane == 0) s_cnt[wv] = min(cnt, WCAP);
        __syncthreads();
        if (t == 0) {
            int acc = 0;
            for (int w = 0; w < 16; ++w) { s_off[w] = acc; acc += s_cnt[w]; }
            s_off[16] = acc;
        }
        __syncthreads();
        float dc = s_dis[c];
        if (lane < s_cnt[wv]) {
            int r = s_r[wv * WCAP + lane];
            s_dr[s_off[wv] + lane]  = r;
            s_nrm[s_off[wv] + lane] = s_dis[r] * s_w[wv * WCAP + lane] * dc;
        }
        __syncthreads();
        int tot = s_off[16];
        if (t < NN) {
            float a = dc * dc * x[(size_t)c * INC + t];          // self-loop term
            #pragma unroll 8
            for (int k = 0; k < tot; ++k)
                a += s_nrm[k] * x[(size_t)s_dr[k] * INC + t];
            agg[(size_t)c * INC + t] = a;                        // plain store
        }
    }
}

// D2: per node c — wave-parallel matvec (cc split across waves, coalesced W reads,
// LDS-atomic merge; lane0 covers odd column 128), ELU, final linear
__global__ __launch_bounds__(1024) void k_fin(
    const float* __restrict__ agg, const float* __restrict__ W,
    const float* __restrict__ cb, const float* __restrict__ lw,
    const float* __restrict__ lb, float* __restrict__ out)
{
    __shared__ float s_a[NN];
    __shared__ float s_g[NN];
    __shared__ float s_h[NN];
    int c = blockIdx.x, t = threadIdx.x;
    int wv = t >> 6, lane = t & 63;

    if (t < NN) { s_a[t] = agg[(size_t)c * INC + t]; s_g[t] = cb[t]; }
    __syncthreads();

    // partial matvec: wave wv covers cc = wv, wv+16, ... (~9 each, independent loads)
    // columns: lane -> [0,64), lane+64 -> [64,128), lane0 extra -> 128
    float p0 = 0.f, p1 = 0.f, p2 = 0.f;
    for (int cc = wv; cc < NN; cc += 16) {
        float av = s_a[cc];
        const float* wr = W + (size_t)cc * INC;
        p0 += av * wr[lane];
        p1 += av * wr[lane + 64];
        if (lane == 0) p2 += av * wr[128];
    }
    atomicAdd(&s_g[lane], p0);
    atomicAdd(&s_g[lane + 64], p1);
    if (lane == 0) atomicAdd(&s_g[128], p2);
    __syncthreads();
    if (t < NN) { float g = s_g[t]; s_h[t] = (g > 0.f) ? g : expm1f(g); }   // ELU
    __syncthreads();

    // final linear: wave per output feature (lw rows coalesced)
    for (int f = wv; f < OUTC; f += 16) {
        const float* wrow = lw + (size_t)f * INC;
        float a = 0.f;
        for (int cc = lane; cc < INC; cc += 64) a += s_h[cc] * wrow[cc];
        for (int o = 32; o; o >>= 1) a += __shfl_xor(a, o, 64);
        if (lane == 0) out[(size_t)c * OUTC + f] = a + lb[f];
    }
}

extern "C" void kernel_launch(void* const* d_in, const int* in_sizes, int n_in,
                              void* d_out, int out_size, void* d_ws, size_t ws_size,
                              hipStream_t stream)
{
    const float* x   = (const float*)d_in[0];
    const int*   ei  = (const int*)d_in[1];
    const float* ew  = (const float*)d_in[2];
    const float* pp  = (const float*)d_in[3];
    const float* W0  = (const float*)d_in[4];
    const float* wih = (const float*)d_in[5];
    const float* whh = (const float*)d_in[6];
    const float* bih = (const float*)d_in[7];
    const float* bhh = (const float*)d_in[8];
    const float* cb  = (const float*)d_in[9];
    const float* lw  = (const float*)d_in[10];
    const float* lb  = (const float*)d_in[11];
    float* out = (float*)d_out;

    char* ws = (char*)d_ws;
    float* W   = (float*)(ws + 0);          // 129*129 f32 (66564 B, pad to 69632)
    float* agg = (float*)(ws + 69632);      // 129*129 f32

    k_big<<<NGRU + NN, 1024, 0, stream>>>(
        x, ei, ew, pp, W0, wih, whh, bih, bhh, W, agg);

    k_fin<<<NN, 1024, 0, stream>>>(agg, W, cb, lw, lb, out);
}

// Round 13
// 32.516 us; speedup vs baseline: 1.6876x; 1.6876x over previous
//
#include <hip/hip_runtime.h>
#include <math.h>

#define NN 129
#define INC 129
#define OUTC 64
#define NE 4096
#define WCAP 32         // per-wave edge-list capacity (mean ~2, max ~10)

__device__ __forceinline__ float sigmf(float x) { return 1.0f / (1.0f + expf(-x)); }

// D1: block 0 -> scores (ILP-batched wave dots) + stable descending perm;
//     blocks 1..129 -> per-target-node gather -> agg row (local deg, no global atomics)
__global__ __launch_bounds__(1024) void k_prep(
    const float* __restrict__ x, const int* __restrict__ ei,
    const float* __restrict__ ew, const float* __restrict__ p,
    float* __restrict__ score, int* __restrict__ perm, float* __restrict__ agg)
{
    int b = blockIdx.x, t = threadIdx.x;
    int wv = t >> 6, lane = t & 63;
    const int* row = ei;
    const int* col = ei + NE;

    if (b == 0) {
        __shared__ float s_sc[NN];

        float pv0 = p[lane];
        float pv1 = p[lane + 64];              // lane+64 in [64,127] < 129, safe
        float pv2 = p[128];                    // odd tail column, handled by lane 0
        float pn = pv0 * pv0 + pv1 * pv1;
        if (lane == 0) pn += pv2 * pv2;

        // 9 independent dot partials per wave (nodes wv, wv+16, ..., guarded)
        float acc[9];
        #pragma unroll
        for (int k = 0; k < 9; ++k) {
            int n = wv + k * 16;
            float a = 0.f;
            if (n < NN) {
                const float* xr = x + (size_t)n * INC;
                a = xr[lane] * pv0 + xr[lane + 64] * pv1;
                if (lane == 0) a += xr[128] * pv2;     // tail column
            }
            acc[k] = a;
        }
        // interleaved butterfly reduces (ILP across the 10 chains)
        #pragma unroll
        for (int o = 32; o; o >>= 1) {
            #pragma unroll
            for (int k = 0; k < 9; ++k) acc[k] += __shfl_xor(acc[k], o, 64);
            pn += __shfl_xor(pn, o, 64);
        }
        float rinv = 1.0f / sqrtf(pn);
        if (lane == 0) {
            #pragma unroll
            for (int k = 0; k < 9; ++k) {
                int n = wv + k * 16;
                if (n < NN) s_sc[n] = acc[k];
            }
        }
        __syncthreads();
        if (t < NN) {
            float sc = tanhf(s_sc[t] * rinv);
            s_sc[t] = sc;
            score[t] = sc;
        }
        __syncthreads();
        if (t < NN) {
            float my = s_sc[t];
            int rank = 0;
            #pragma unroll 16
            for (int j = 0; j < NN; ++j) {
                float o = s_sc[j];
                rank += (o > my || (o == my && j < t)) ? 1 : 0;   // stable descending
            }
            perm[rank] = t;
        }
    } else {
        // gather block for target node c (independent of score/perm)
        int c = b - 1;
        __shared__ float s_deg[NN];
        __shared__ float s_dis[NN];
        __shared__ int   s_r[16 * WCAP];
        __shared__ float s_w[16 * WCAP];
        __shared__ int   s_cnt[16];
        __shared__ int   s_off[17];
        __shared__ int   s_dr[16 * WCAP];
        __shared__ float s_nrm[16 * WCAP];

        if (t < NN) s_deg[t] = 0.f;
        __syncthreads();
        for (int e = t; e < NE; e += 1024) atomicAdd(&s_deg[col[e]], ew[e]);
        __syncthreads();
        if (t < NN) s_dis[t] = rsqrtf(fmaxf(s_deg[t] + 1.0f, 1e-12f));  // +1 self-loop
        __syncthreads();

        // syncless per-wave ballot edge list: wave wv owns edges [wv*256, wv*256+256)
        int basee = wv * 256;
        int cnt = 0;
        #pragma unroll
        for (int it = 0; it < 4; ++it) {
            int e = basee + it * 64 + lane;
            int rr = row[e];
            float wval = ew[e];
            bool m = (col[e] == c);
            unsigned long long mask = __ballot(m);
            if (m) {
                int pos = cnt + __popcll(mask & ((1ull << lane) - 1));
                if (pos < WCAP) { s_r[wv * WCAP + pos] = rr; s_w[wv * WCAP + pos] = wval; }
            }
            cnt += __popcll(mask);
        }
        if (lane == 0) s_cnt[wv] = min(cnt, WCAP);
        __syncthreads();
        if (t == 0) {
            int acc = 0;
            for (int w = 0; w < 16; ++w) { s_off[w] = acc; acc += s_cnt[w]; }
            s_off[16] = acc;
        }
        __syncthreads();
        float dc = s_dis[c];
        if (lane < s_cnt[wv]) {
            int r = s_r[wv * WCAP + lane];
            s_dr[s_off[wv] + lane]  = r;
            s_nrm[s_off[wv] + lane] = s_dis[r] * s_w[wv * WCAP + lane] * dc;
        }
        __syncthreads();
        int tot = s_off[16];
        if (t < NN) {
            float a = dc * dc * x[(size_t)c * INC + t];          // self-loop term
            #pragma unroll 8
            for (int k = 0; k < tot; ++k)
                a += s_nrm[k] * x[(size_t)s_dr[k] * INC + t];
            agg[(size_t)c * INC + t] = a;                        // plain store
        }
    }
}

// D2: pure GRU, one wave per output element (i,j) — proven r9 pattern
__global__ __launch_bounds__(256) void k_gru(
    const float* __restrict__ x, const float* __restrict__ score,
    const int* __restrict__ perm, const float* __restrict__ W0,
    const float* __restrict__ w_ih, const float* __restrict__ w_hh,
    const float* __restrict__ b_ih, const float* __restrict__ b_hh,
    float* __restrict__ W)
{
    int lane = threadIdx.x & 63;
    int wid = blockIdx.x * 4 + (threadIdx.x >> 6);
    if (wid >= NN * INC) return;
    int i = wid / INC;
    int j = wid - i * INC;
    int pi = perm[i];
    float sc = score[pi];
    const float* xr = x  + (size_t)pi * INC;
    const float* h0 = W0 + (size_t)i * INC;
    const float* wr = w_ih + (size_t)j * INC;
    const float* wz = wr + (size_t)INC * INC;
    const float* wn = wz + (size_t)INC * INC;
    const float* vr = w_hh + (size_t)j * INC;
    const float* vz = vr + (size_t)INC * INC;
    const float* vn = vz + (size_t)INC * INC;

    float sr = 0.f, szv = 0.f, an = 0.f, hn = 0.f;
    for (int c = lane; c < INC; c += 64) {
        float xv = xr[c] * sc;
        float hv = h0[c];
        sr  += xv * wr[c] + hv * vr[c];
        szv += xv * wz[c] + hv * vz[c];
        an  += xv * wn[c];
        hn  += hv * vn[c];
    }
    for (int o = 32; o; o >>= 1) {
        sr  += __shfl_xor(sr,  o, 64);
        szv += __shfl_xor(szv, o, 64);
        an  += __shfl_xor(an,  o, 64);
        hn  += __shfl_xor(hn,  o, 64);
    }
    if (lane == 0) {
        float r    = sigmf(sr  + b_ih[j]           + b_hh[j]);
        float z    = sigmf(szv + b_ih[INC + j]     + b_hh[INC + j]);
        float cand = tanhf(an + b_ih[2 * INC + j] + r * (hn + b_hh[2 * INC + j]));
        W[(size_t)i * INC + j] = (1.0f - z) * cand + z * h0[j];
    }
}

// D3: per node c — wave-parallel matvec (coalesced W reads, LDS-atomic merge,
// lane0 covers column 128), ELU, wave-per-feature final linear
__global__ __launch_bounds__(1024) void k_fin(
    const float* __restrict__ agg, const float* __restrict__ W,
    const float* __restrict__ cb, const float* __restrict__ lw,
    const float* __restrict__ lb, float* __restrict__ out)
{
    __shared__ float s_a[NN];
    __shared__ float s_g[NN];
    __shared__ float s_h[NN];
    int c = blockIdx.x, t = threadIdx.x;
    int wv = t >> 6, lane = t & 63;

    if (t < NN) { s_a[t] = agg[(size_t)c * INC + t]; s_g[t] = cb[t]; }
    __syncthreads();

    // partial matvec: wave wv covers cc = wv, wv+16, ... (~9 each, independent loads)
    float p0 = 0.f, p1 = 0.f, p2 = 0.f;
    for (int cc = wv; cc < NN; cc += 16) {
        float av = s_a[cc];
        const float* wr = W + (size_t)cc * INC;
        p0 += av * wr[lane];
        p1 += av * wr[lane + 64];
        if (lane == 0) p2 += av * wr[128];
    }
    atomicAdd(&s_g[lane], p0);
    atomicAdd(&s_g[lane + 64], p1);
    if (lane == 0) atomicAdd(&s_g[128], p2);
    __syncthreads();
    if (t < NN) { float g = s_g[t]; s_h[t] = (g > 0.f) ? g : expm1f(g); }   // ELU
    __syncthreads();

    // final linear: wave per output feature (lw rows coalesced)
    for (int f = wv; f < OUTC; f += 16) {
        const float* wrow = lw + (size_t)f * INC;
        float a = 0.f;
        for (int cc = lane; cc < INC; cc += 64) a += s_h[cc] * wrow[cc];
        for (int o = 32; o; o >>= 1) a += __shfl_xor(a, o, 64);
        if (lane == 0) out[(size_t)c * OUTC + f] = a + lb[f];
    }
}

extern "C" void kernel_launch(void* const* d_in, const int* in_sizes, int n_in,
                              void* d_out, int out_size, void* d_ws, size_t ws_size,
                              hipStream_t stream)
{
    const float* x   = (const float*)d_in[0];
    const int*   ei  = (const int*)d_in[1];
    const float* ew  = (const float*)d_in[2];
    const float* pp  = (const float*)d_in[3];
    const float* W0  = (const float*)d_in[4];
    const float* wih = (const float*)d_in[5];
    const float* whh = (const float*)d_in[6];
    const float* bih = (const float*)d_in[7];
    const float* bhh = (const float*)d_in[8];
    const float* cb  = (const float*)d_in[9];
    const float* lw  = (const float*)d_in[10];
    const float* lb  = (const float*)d_in[11];
    float* out = (float*)d_out;

    char* ws = (char*)d_ws;
    float* score = (float*)(ws + 0);               // 129 f32
    int*   perm  = (int*)  (ws + 640);             // 129 i32
    float* W     = (float*)(ws + 2048);            // 129*129 f32
    float* agg   = (float*)(ws + 2048 + 69632);    // 129*129 f32

    k_prep<<<NN + 1, 1024, 0, stream>>>(x, ei, ew, pp, score, perm, agg);

    int gru_blocks = (NN * INC + 3) / 4;           // 4161
    k_gru<<<gru_blocks, 256, 0, stream>>>(x, score, perm, W0, wih, whh, bih, bhh, W);

    k_fin<<<NN, 1024, 0, stream>>>(agg, W, cb, lw, lb, out);
}

// Round 14
// 32.479 us; speedup vs baseline: 1.6895x; 1.0011x over previous
//
#include <hip/hip_runtime.h>
#include <math.h>

#define NN 129
#define INC 129
#define OUTC 64
#define NE 4096
#define WCAP 32         // per-wave edge-list capacity (mean ~2, max ~10)

__device__ __forceinline__ float sigmf(float x) { return 1.0f / (1.0f + expf(-x)); }

// D1: block 0 -> scores (ILP-batched wave dots) + stable descending perm;
//     blocks 1..129 -> per-target-node gather -> agg row (local deg, no global atomics)
__global__ __launch_bounds__(1024) void k_prep(
    const float* __restrict__ x, const int* __restrict__ ei,
    const float* __restrict__ ew, const float* __restrict__ p,
    float* __restrict__ score, int* __restrict__ perm, float* __restrict__ agg)
{
    int b = blockIdx.x, t = threadIdx.x;
    int wv = t >> 6, lane = t & 63;
    const int* row = ei;
    const int* col = ei + NE;

    if (b == 0) {
        __shared__ float s_sc[NN];

        float pv0 = p[lane];
        float pv1 = p[lane + 64];              // lane+64 in [64,127] < 129, safe
        float pv2 = p[128];                    // odd tail column, handled by lane 0
        float pn = pv0 * pv0 + pv1 * pv1;
        if (lane == 0) pn += pv2 * pv2;

        // 9 independent dot partials per wave (nodes wv, wv+16, ..., guarded)
        float acc[9];
        #pragma unroll
        for (int k = 0; k < 9; ++k) {
            int n = wv + k * 16;
            float a = 0.f;
            if (n < NN) {
                const float* xr = x + (size_t)n * INC;
                a = xr[lane] * pv0 + xr[lane + 64] * pv1;
                if (lane == 0) a += xr[128] * pv2;     // tail column
            }
            acc[k] = a;
        }
        // interleaved butterfly reduces (ILP across the 10 chains)
        #pragma unroll
        for (int o = 32; o; o >>= 1) {
            #pragma unroll
            for (int k = 0; k < 9; ++k) acc[k] += __shfl_xor(acc[k], o, 64);
            pn += __shfl_xor(pn, o, 64);
        }
        float rinv = 1.0f / sqrtf(pn);
        if (lane == 0) {
            #pragma unroll
            for (int k = 0; k < 9; ++k) {
                int n = wv + k * 16;
                if (n < NN) s_sc[n] = acc[k];
            }
        }
        __syncthreads();
        if (t < NN) {
            float sc = tanhf(s_sc[t] * rinv);
            s_sc[t] = sc;
            score[t] = sc;
        }
        __syncthreads();
        if (t < NN) {
            float my = s_sc[t];
            int rank = 0;
            #pragma unroll 16
            for (int j = 0; j < NN; ++j) {
                float o = s_sc[j];
                rank += (o > my || (o == my && j < t)) ? 1 : 0;   // stable descending
            }
            perm[rank] = t;
        }
    } else {
        // gather block for target node c (independent of score/perm)
        int c = b - 1;
        __shared__ float s_deg[NN];
        __shared__ float s_dis[NN];
        __shared__ int   s_r[16 * WCAP];
        __shared__ float s_w[16 * WCAP];
        __shared__ int   s_cnt[16];
        __shared__ int   s_off[17];
        __shared__ int   s_dr[16 * WCAP];
        __shared__ float s_nrm[16 * WCAP];

        if (t < NN) s_deg[t] = 0.f;
        __syncthreads();
        for (int e = t; e < NE; e += 1024) atomicAdd(&s_deg[col[e]], ew[e]);
        __syncthreads();
        if (t < NN) s_dis[t] = rsqrtf(fmaxf(s_deg[t] + 1.0f, 1e-12f));  // +1 self-loop
        __syncthreads();

        // syncless per-wave ballot edge list: wave wv owns edges [wv*256, wv*256+256)
        int basee = wv * 256;
        int cnt = 0;
        #pragma unroll
        for (int it = 0; it < 4; ++it) {
            int e = basee + it * 64 + lane;
            int rr = row[e];
            float wval = ew[e];
            bool m = (col[e] == c);
            unsigned long long mask = __ballot(m);
            if (m) {
                int pos = cnt + __popcll(mask & ((1ull << lane) - 1));
                if (pos < WCAP) { s_r[wv * WCAP + pos] = rr; s_w[wv * WCAP + pos] = wval; }
            }
            cnt += __popcll(mask);
        }
        if (lane == 0) s_cnt[wv] = min(cnt, WCAP);
        __syncthreads();
        if (t == 0) {
            int acc = 0;
            for (int w = 0; w < 16; ++w) { s_off[w] = acc; acc += s_cnt[w]; }
            s_off[16] = acc;
        }
        __syncthreads();
        float dc = s_dis[c];
        if (lane < s_cnt[wv]) {
            int r = s_r[wv * WCAP + lane];
            s_dr[s_off[wv] + lane]  = r;
            s_nrm[s_off[wv] + lane] = s_dis[r] * s_w[wv * WCAP + lane] * dc;
        }
        __syncthreads();
        int tot = s_off[16];
        if (t < NN) {
            float a = dc * dc * x[(size_t)c * INC + t];          // self-loop term
            #pragma unroll 8
            for (int k = 0; k < tot; ++k)
                a += s_nrm[k] * x[(size_t)s_dr[k] * INC + t];
            agg[(size_t)c * INC + t] = a;                        // plain store
        }
    }
}

// D2: pure GRU, one wave per output element. Mapping: i = wid % NN (fast),
// j = wid / NN (slow) -> the 4 waves of a block share j => the 6 weight rows
// + biases hit L1, and ~33 consecutive blocks reuse them through L2.
__global__ __launch_bounds__(256) void k_gru(
    const float* __restrict__ x, const float* __restrict__ score,
    const int* __restrict__ perm, const float* __restrict__ W0,
    const float* __restrict__ w_ih, const float* __restrict__ w_hh,
    const float* __restrict__ b_ih, const float* __restrict__ b_hh,
    float* __restrict__ W)
{
    int lane = threadIdx.x & 63;
    int wid = blockIdx.x * 4 + (threadIdx.x >> 6);
    if (wid >= NN * INC) return;
    int j = wid / NN;              // weight row (shared within block)
    int i = wid - j * NN;          // state row (fast-varying)
    int pi = perm[i];
    float sc = score[pi];
    const float* xr = x  + (size_t)pi * INC;
    const float* h0 = W0 + (size_t)i * INC;
    const float* wr = w_ih + (size_t)j * INC;
    const float* wz = wr + (size_t)INC * INC;
    const float* wn = wz + (size_t)INC * INC;
    const float* vr = w_hh + (size_t)j * INC;
    const float* vz = vr + (size_t)INC * INC;
    const float* vn = vz + (size_t)INC * INC;

    float sr = 0.f, szv = 0.f, an = 0.f, hn = 0.f;
    for (int c = lane; c < INC; c += 64) {
        float xv = xr[c] * sc;
        float hv = h0[c];
        sr  += xv * wr[c] + hv * vr[c];
        szv += xv * wz[c] + hv * vz[c];
        an  += xv * wn[c];
        hn  += hv * vn[c];
    }
    for (int o = 32; o; o >>= 1) {
        sr  += __shfl_xor(sr,  o, 64);
        szv += __shfl_xor(szv, o, 64);
        an  += __shfl_xor(an,  o, 64);
        hn  += __shfl_xor(hn,  o, 64);
    }
    if (lane == 0) {
        float r    = sigmf(sr  + b_ih[j]           + b_hh[j]);
        float z    = sigmf(szv + b_ih[INC + j]     + b_hh[INC + j]);
        float cand = tanhf(an + b_ih[2 * INC + j] + r * (hn + b_hh[2 * INC + j]));
        W[(size_t)i * INC + j] = (1.0f - z) * cand + z * h0[j];
    }
}

// D3: per node c — wave-parallel matvec (coalesced W reads, LDS-atomic merge,
// lane0 covers column 128), ELU, wave-per-feature final linear
__global__ __launch_bounds__(1024) void k_fin(
    const float* __restrict__ agg, const float* __restrict__ W,
    const float* __restrict__ cb, const float* __restrict__ lw,
    const float* __restrict__ lb, float* __restrict__ out)
{
    __shared__ float s_a[NN];
    __shared__ float s_g[NN];
    __shared__ float s_h[NN];
    int c = blockIdx.x, t = threadIdx.x;
    int wv = t >> 6, lane = t & 63;

    if (t < NN) { s_a[t] = agg[(size_t)c * INC + t]; s_g[t] = cb[t]; }
    __syncthreads();

    // partial matvec: wave wv covers cc = wv, wv+16, ... (~9 each, independent loads)
    float p0 = 0.f, p1 = 0.f, p2 = 0.f;
    for (int cc = wv; cc < NN; cc += 16) {
        float av = s_a[cc];
        const float* wr = W + (size_t)cc * INC;
        p0 += av * wr[lane];
        p1 += av * wr[lane + 64];
        if (lane == 0) p2 += av * wr[128];
    }
    atomicAdd(&s_g[lane], p0);
    atomicAdd(&s_g[lane + 64], p1);
    if (lane == 0) atomicAdd(&s_g[128], p2);
    __syncthreads();
    if (t < NN) { float g = s_g[t]; s_h[t] = (g > 0.f) ? g : expm1f(g); }   // ELU
    __syncthreads();

    // final linear: wave per output feature (lw rows coalesced)
    for (int f = wv; f < OUTC; f += 16) {
        const float* wrow = lw + (size_t)f * INC;
        float a = 0.f;
        for (int cc = lane; cc < INC; cc += 64) a += s_h[cc] * wrow[cc];
        for (int o = 32; o; o >>= 1) a += __shfl_xor(a, o, 64);
        if (lane == 0) out[(size_t)c * OUTC + f] = a + lb[f];
    }
}

extern "C" void kernel_launch(void* const* d_in, const int* in_sizes, int n_in,
                              void* d_out, int out_size, void* d_ws, size_t ws_size,
                              hipStream_t stream)
{
    const float* x   = (const float*)d_in[0];
    const int*   ei  = (const int*)d_in[1];
    const float* ew  = (const float*)d_in[2];
    const float* pp  = (const float*)d_in[3];
    const float* W0  = (const float*)d_in[4];
    const float* wih = (const float*)d_in[5];
    const float* whh = (const float*)d_in[6];
    const float* bih = (const float*)d_in[7];
    const float* bhh = (const float*)d_in[8];
    const float* cb  = (const float*)d_in[9];
    const float* lw  = (const float*)d_in[10];
    const float* lb  = (const float*)d_in[11];
    float* out = (float*)d_out;

    char* ws = (char*)d_ws;
    float* score = (float*)(ws + 0);               // 129 f32
    int*   perm  = (int*)  (ws + 640);             // 129 i32
    float* W     = (float*)(ws + 2048);            // 129*129 f32
    float* agg   = (float*)(ws + 2048 + 69632);    // 129*129 f32

    k_prep<<<NN + 1, 1024, 0, stream>>>(x, ei, ew, pp, score, perm, agg);

    int gru_blocks = (NN * INC + 3) / 4;           // 4161
    k_gru<<<gru_blocks, 256, 0, stream>>>(x, score, perm, W0, wih, whh, bih, bhh, W);

    k_fin<<<NN, 1024, 0, stream>>>(agg, W, cb, lw, lb, out);
}